// Round 8
// baseline (530.577 us; speedup 1.0000x reference)
//
#include <hip/hip_runtime.h>
#include <hip/hip_cooperative_groups.h>

namespace cg = cooperative_groups;

#define NN    100000
#define NE    640000
#define DIM   128
#define NPT   32    // nodes per fused tile
#define PAD   4     // LDS row pad: stride 528 B, 16B-aligned
#define WCH   16    // W chunk width -> Ws 8.4 KB; total LDS 25.3 KB, 6 blk/CU
#define CGRID 1024  // cooperative grid (4 blocks/CU, co-resident)
#define CH    98    // ceil((NN+1)/CGRID)

// ws layout (4-byte elems):
//   cnts [0, NN)  offs [NN, 2NN+4)  curs [2NN+4, 3NN+4)
//   esrc [3NN+4, +NE)  blksum [+CGRID]   total ~3.77 MB

// ---------------------------------------------------------------------------
// 1) Cooperative CSR build: zero -> hist -> scan -> bin, one launch.
// ---------------------------------------------------------------------------
__global__ __launch_bounds__(256) void build_csr_k(
    const int* __restrict__ ei,         // [2][NE] int32
    unsigned* __restrict__ cnts,
    unsigned* __restrict__ offs,        // [NN+1]
    unsigned* __restrict__ curs,        // [NN]
    int* __restrict__ esrc,             // [NE]
    unsigned* __restrict__ blksum)      // [CGRID]
{
    cg::grid_group grid = cg::this_grid();
    __shared__ unsigned ls[128];
    __shared__ unsigned lsum[4];

    const int t    = threadIdx.x;
    const int bid  = blockIdx.x;
    const int gid  = bid * 256 + t;
    const int nthr = CGRID * 256;

    // Phase 0: zero counters
    for (int i = gid; i < NN; i += nthr) cnts[i] = 0u;
    grid.sync();

    // Phase 1: histogram of targets
    for (int e = gid; e < NE; e += nthr) {
        int tg = ei[NE + e];
        if ((unsigned)tg < NN) atomicAdd(&cnts[tg], 1u);
    }
    grid.sync();

    // Phase 2a: per-block inclusive scan of CH elems of the (NN+1) domain
    const int beg = bid * CH;
    unsigned myv = 0;
    if (t < CH) {
        int i = beg + t;
        myv = (i < NN) ? cnts[i] : 0u;
    }
    if (t < 128) ls[t] = (t < CH) ? myv : 0u;
    __syncthreads();
    for (int off = 1; off < 128; off <<= 1) {
        unsigned u = (t >= off && t < 128) ? ls[t - off] : 0u;
        __syncthreads();
        if (t < 128) ls[t] += u;
        __syncthreads();
    }
    if (t == 0) blksum[bid] = ls[127];
    grid.sync();

    // Phase 2b: base = sum blksum[0..bid-1]; write offs/curs
    unsigned part = 0;
    for (int j = t; j < bid; j += 256) part += blksum[j];
    #pragma unroll
    for (int off = 32; off; off >>= 1) part += __shfl_down(part, off);
    if ((t & 63) == 0) lsum[t >> 6] = part;
    __syncthreads();
    unsigned base = lsum[0] + lsum[1] + lsum[2] + lsum[3];
    if (t < CH) {
        int i = beg + t;
        if (i <= NN) {
            unsigned ov = base + ls[t] - myv;   // exclusive
            offs[i] = ov;
            if (i < NN) curs[i] = ov;
        }
    }
    grid.sync();

    // Phase 3: bin edges by target
    for (int e = gid; e < NE; e += nthr) {
        int s  = ei[e];
        int tg = ei[NE + e];
        if ((unsigned)s >= NN || (unsigned)tg >= NN) continue;
        unsigned pos = atomicAdd(&curs[tg], 1u);
        esrc[pos] = s;
    }
}

// ---------------------------------------------------------------------------
// 2) Fused mean + linear + residual:
//    out[n] = x[n] + b + (mean over CSR segment of x[src]) @ W^T
//    LDS: Ws[16][132] 8.4 KB + mean_s[32][132] 16.9 KB = 25.3 KB
//    -> 6 blocks/CU (24 waves).
// ---------------------------------------------------------------------------
__global__ __launch_bounds__(256) void fused_k(
    const float* __restrict__ x,
    const float* __restrict__ W,        // [o][i] row-major, 128x128
    const float* __restrict__ b,
    const unsigned* __restrict__ offs,
    const int* __restrict__ esrc,
    float* __restrict__ out)
{
    __shared__ float Ws[WCH][DIM + PAD];      // Ws[il][o] = W[o][c*WCH+il]
    __shared__ float mean_s[NPT][DIM + PAD];

    const int t    = threadIdx.x;
    const int base = blockIdx.x * NPT;

    // Compute 32 mean rows directly: 8 threads/node, 16 floats each.
    {
        int sn   = t >> 3;
        int so   = (t & 7) * 16;
        int node = base + sn;
        unsigned beg = offs[node], end = offs[node + 1];
        float4 a0 = make_float4(0.f, 0.f, 0.f, 0.f), a1 = a0, a2 = a0, a3 = a0;
        int s = (beg < end) ? esrc[beg] : 0;
        for (unsigned j = beg; j < end; ++j) {
            int snext = (j + 1 < end) ? esrc[j + 1] : 0;
            const float4* xr = reinterpret_cast<const float4*>(x + (size_t)s * DIM + so);
            float4 g0 = xr[0], g1 = xr[1], g2 = xr[2], g3 = xr[3];
            a0.x += g0.x; a0.y += g0.y; a0.z += g0.z; a0.w += g0.w;
            a1.x += g1.x; a1.y += g1.y; a1.z += g1.z; a1.w += g1.w;
            a2.x += g2.x; a2.y += g2.y; a2.z += g2.z; a2.w += g2.w;
            a3.x += g3.x; a3.y += g3.y; a3.z += g3.z; a3.w += g3.w;
            s = snext;
        }
        float inv = 1.0f / fmaxf((float)(end - beg), 1.0f);
        a0.x *= inv; a0.y *= inv; a0.z *= inv; a0.w *= inv;
        a1.x *= inv; a1.y *= inv; a1.z *= inv; a1.w *= inv;
        a2.x *= inv; a2.y *= inv; a2.z *= inv; a2.w *= inv;
        a3.x *= inv; a3.y *= inv; a3.z *= inv; a3.w *= inv;
        *reinterpret_cast<float4*>(&mean_s[sn][so +  0]) = a0;
        *reinterpret_cast<float4*>(&mean_s[sn][so +  4]) = a1;
        *reinterpret_cast<float4*>(&mean_s[sn][so +  8]) = a2;
        *reinterpret_cast<float4*>(&mean_s[sn][so + 12]) = a3;
    }

    const int og = (t & 31) * 4;    // 4 consecutive outputs per thread
    const int ng = (t >> 5) * 4;    // 4 consecutive nodes per thread

    float4 acc[4];
    #pragma unroll
    for (int n = 0; n < 4; ++n) acc[n] = make_float4(0.f, 0.f, 0.f, 0.f);

    for (int c = 0; c < DIM / WCH; ++c) {
        __syncthreads();   // (c=0: also covers mean_s staging)
        // Stage W chunk transposed: 2048 elements, coalesced global reads
        #pragma unroll
        for (int k = 0; k < (DIM * WCH) / 256; ++k) {
            int idx = t + k * 256;      // 0..2047
            int o   = idx >> 4;         // 0..127
            int il  = idx & 15;         // 0..15
            Ws[il][o] = W[o * DIM + c * WCH + il];
        }
        __syncthreads();

        #pragma unroll
        for (int i = 0; i < WCH; i += 4) {
            float4 m4[4];
            #pragma unroll
            for (int n = 0; n < 4; ++n)
                m4[n] = *reinterpret_cast<const float4*>(&mean_s[ng + n][c * WCH + i]);
            #pragma unroll
            for (int j = 0; j < 4; ++j) {
                float4 w = *reinterpret_cast<const float4*>(&Ws[i + j][og]);
                #pragma unroll
                for (int n = 0; n < 4; ++n) {
                    float m = (j == 0) ? m4[n].x : (j == 1) ? m4[n].y
                            : (j == 2) ? m4[n].z : m4[n].w;
                    acc[n].x += m * w.x;
                    acc[n].y += m * w.y;
                    acc[n].z += m * w.z;
                    acc[n].w += m * w.w;
                }
            }
        }
    }

    float4 bv = *reinterpret_cast<const float4*>(b + og);
    #pragma unroll
    for (int n = 0; n < 4; ++n) {
        int node = base + ng + n;
        float4 xv = *reinterpret_cast<const float4*>(x + (size_t)node * DIM + og);
        float4 o4;
        o4.x = xv.x + bv.x + acc[n].x;
        o4.y = xv.y + bv.y + acc[n].y;
        o4.z = xv.z + bv.z + acc[n].z;
        o4.w = xv.w + bv.w + acc[n].w;
        *reinterpret_cast<float4*>(out + (size_t)node * DIM + og) = o4;
    }
}

extern "C" void kernel_launch(void* const* d_in, const int* in_sizes, int n_in,
                              void* d_out, int out_size, void* d_ws, size_t ws_size,
                              hipStream_t stream) {
    const float* x  = (const float*)d_in[0];
    const int*   ei = (const int*)d_in[1];     // int32 per harness contract
    const float* W  = (const float*)d_in[2];
    const float* b  = (const float*)d_in[3];
    float* out = (float*)d_out;

    unsigned* cnts   = (unsigned*)d_ws;
    unsigned* offs   = cnts + NN;              // NN+1 used (padded to NN+4)
    unsigned* curs   = cnts + 2 * NN + 4;      // NN
    int*      esrc   = (int*)(cnts + 3 * NN + 4);   // NE
    unsigned* blksum = (unsigned*)(esrc + NE);      // CGRID

    void* args[] = { (void*)&ei, (void*)&cnts, (void*)&offs,
                     (void*)&curs, (void*)&esrc, (void*)&blksum };
    hipLaunchCooperativeKernel((const void*)build_csr_k,
                               dim3(CGRID), dim3(256), args, 0, stream);

    fused_k<<<NN / NPT, 256, 0, stream>>>(x, W, b, offs, esrc, out);
}

// Round 9
// 165.804 us; speedup vs baseline: 3.2000x; 3.2000x over previous
//
#include <hip/hip_runtime.h>

#define NN    100000
#define NE    640000
#define DIM   128
#define NPT   32    // nodes per fused tile
#define PAD   4     // LDS row pad: stride 528 B, 16B-aligned
#define WCH   16    // W chunk width -> Ws 8.4 KB; total LDS 25.3 KB, 6 blk/CU
#define TILE  1024  // scan tile (elements per block)
#define NBLK  98    // ceil(NN / TILE)

// ws layout (4-byte elems), 16B-aligned sections:
//   cnts [0, NN)          offs [NN, 2NN+4)       (NN+1 used)
//   curs [2NN+4, 3NN+4)   esrc [3NN+4, 3NN+4+NE)
//   blksum [+128]         total ~3.77 MB

// ---------------------------------------------------------------------------
// 1) Histogram of targets: 640K int atomics on 100K counters.
// ---------------------------------------------------------------------------
__global__ __launch_bounds__(256) void hist_k(
    const int* __restrict__ ei, unsigned* __restrict__ cnts)
{
    int e = blockIdx.x * 256 + threadIdx.x;
    if (e >= NE) return;
    int t = ei[NE + e];
    if ((unsigned)t >= NN) return;
    atomicAdd(&cnts[t], 1u);
}

// ---------------------------------------------------------------------------
// 2a) Per-block sums of 1024-elem tiles (uint4 loads, shuffle reduce).
// ---------------------------------------------------------------------------
__global__ __launch_bounds__(256) void scan_a_k(
    const unsigned* __restrict__ cnts, unsigned* __restrict__ blksum)
{
    __shared__ unsigned red[4];
    int t    = threadIdx.x;
    int base = blockIdx.x * TILE + t * 4;
    unsigned v = 0;
    if (base + 3 < NN) {
        uint4 u = *reinterpret_cast<const uint4*>(cnts + base);
        v = u.x + u.y + u.z + u.w;
    } else {
        for (int k = 0; k < 4; ++k) if (base + k < NN) v += cnts[base + k];
    }
    #pragma unroll
    for (int off = 32; off; off >>= 1) v += __shfl_down(v, off);
    if ((t & 63) == 0) red[t >> 6] = v;
    __syncthreads();
    if (t == 0) blksum[blockIdx.x] = red[0] + red[1] + red[2] + red[3];
}

// ---------------------------------------------------------------------------
// 2b) Per-block scan (+ inline base from blksum) -> offs, curs.
//     Each block sums blksum[0..bid) itself (<=98 values) - no scan_b launch.
//     Last block also writes offs[NN].
// ---------------------------------------------------------------------------
__global__ __launch_bounds__(256) void scan_c_k(
    const unsigned* __restrict__ cnts,
    const unsigned* __restrict__ blksum,
    unsigned* __restrict__ offs,
    unsigned* __restrict__ curs)
{
    __shared__ unsigned ps[256];
    __shared__ unsigned lsum[4];
    int t    = threadIdx.x;
    int bid  = blockIdx.x;
    int base = bid * TILE + t * 4;

    // base offset = sum of preceding block sums
    unsigned part = 0;
    for (int j = t; j < bid; j += 256) part += blksum[j];
    #pragma unroll
    for (int off = 32; off; off >>= 1) part += __shfl_down(part, off);
    if ((t & 63) == 0) lsum[t >> 6] = part;

    unsigned v0 = 0, v1 = 0, v2 = 0, v3 = 0;
    if (base + 3 < NN) {
        uint4 u = *reinterpret_cast<const uint4*>(cnts + base);
        v0 = u.x; v1 = u.y; v2 = u.z; v3 = u.w;
    } else {
        if (base     < NN) v0 = cnts[base];
        if (base + 1 < NN) v1 = cnts[base + 1];
        if (base + 2 < NN) v2 = cnts[base + 2];
    }
    ps[t] = v0 + v1 + v2 + v3;
    __syncthreads();
    for (int off = 1; off < 256; off <<= 1) {
        unsigned u = (t >= off) ? ps[t - off] : 0u;
        __syncthreads();
        ps[t] += u;
        __syncthreads();
    }
    unsigned blkbase = lsum[0] + lsum[1] + lsum[2] + lsum[3];
    unsigned run = blkbase + ((t == 0) ? 0u : ps[t - 1]);
    unsigned o0 = run, o1 = o0 + v0, o2 = o1 + v1, o3 = o2 + v2;
    if (base + 3 < NN) {
        *reinterpret_cast<uint4*>(offs + base) = make_uint4(o0, o1, o2, o3);
        *reinterpret_cast<uint4*>(curs + base) = make_uint4(o0, o1, o2, o3);
    } else {
        if (base     < NN) { offs[base]     = o0; curs[base]     = o0; }
        if (base + 1 < NN) { offs[base + 1] = o1; curs[base + 1] = o1; }
        if (base + 2 < NN) { offs[base + 2] = o2; curs[base + 2] = o2; }
    }
    if (bid == NBLK - 1 && t == 255) offs[NN] = blkbase + ps[255];
}

// ---------------------------------------------------------------------------
// 3) Bin edges by target: esrc[slot] = src.
// ---------------------------------------------------------------------------
__global__ __launch_bounds__(256) void bin_k(
    const int* __restrict__ ei,
    unsigned* __restrict__ curs,
    int* __restrict__ esrc)
{
    int e = blockIdx.x * 256 + threadIdx.x;
    if (e >= NE) return;
    int s = ei[e];
    int t = ei[NE + e];
    if ((unsigned)s >= NN || (unsigned)t >= NN) return;
    unsigned pos = atomicAdd(&curs[t], 1u);
    esrc[pos] = s;
}

// ---------------------------------------------------------------------------
// 4) Fused mean + linear + residual:
//    out[n] = x[n] + b + (mean over CSR segment of x[src]) @ W^T
//    LDS: Ws[16][132] 8.4 KB + mean_s[32][132] 16.9 KB = 25.3 KB
//    -> 6 blocks/CU (24 waves, 75% theoretical).
// ---------------------------------------------------------------------------
__global__ __launch_bounds__(256) void fused_k(
    const float* __restrict__ x,
    const float* __restrict__ W,        // [o][i] row-major, 128x128
    const float* __restrict__ b,
    const unsigned* __restrict__ offs,
    const int* __restrict__ esrc,
    float* __restrict__ out)
{
    __shared__ float Ws[WCH][DIM + PAD];      // Ws[il][o] = W[o][c*WCH+il]
    __shared__ float mean_s[NPT][DIM + PAD];

    const int t    = threadIdx.x;
    const int base = blockIdx.x * NPT;

    // Compute 32 mean rows directly: 8 threads/node, 16 floats each.
    // One-ahead esrc prefetch breaks the index->address serial chain.
    {
        int sn   = t >> 3;
        int so   = (t & 7) * 16;
        int node = base + sn;
        unsigned beg = offs[node], end = offs[node + 1];
        float4 a0 = make_float4(0.f, 0.f, 0.f, 0.f), a1 = a0, a2 = a0, a3 = a0;
        int s = (beg < end) ? esrc[beg] : 0;
        for (unsigned j = beg; j < end; ++j) {
            int snext = (j + 1 < end) ? esrc[j + 1] : 0;
            const float4* xr = reinterpret_cast<const float4*>(x + (size_t)s * DIM + so);
            float4 g0 = xr[0], g1 = xr[1], g2 = xr[2], g3 = xr[3];
            a0.x += g0.x; a0.y += g0.y; a0.z += g0.z; a0.w += g0.w;
            a1.x += g1.x; a1.y += g1.y; a1.z += g1.z; a1.w += g1.w;
            a2.x += g2.x; a2.y += g2.y; a2.z += g2.z; a2.w += g2.w;
            a3.x += g3.x; a3.y += g3.y; a3.z += g3.z; a3.w += g3.w;
            s = snext;
        }
        float inv = 1.0f / fmaxf((float)(end - beg), 1.0f);
        a0.x *= inv; a0.y *= inv; a0.z *= inv; a0.w *= inv;
        a1.x *= inv; a1.y *= inv; a1.z *= inv; a1.w *= inv;
        a2.x *= inv; a2.y *= inv; a2.z *= inv; a2.w *= inv;
        a3.x *= inv; a3.y *= inv; a3.z *= inv; a3.w *= inv;
        *reinterpret_cast<float4*>(&mean_s[sn][so +  0]) = a0;
        *reinterpret_cast<float4*>(&mean_s[sn][so +  4]) = a1;
        *reinterpret_cast<float4*>(&mean_s[sn][so +  8]) = a2;
        *reinterpret_cast<float4*>(&mean_s[sn][so + 12]) = a3;
    }

    const int og = (t & 31) * 4;    // 4 consecutive outputs per thread
    const int ng = (t >> 5) * 4;    // 4 consecutive nodes per thread

    float4 acc[4];
    #pragma unroll
    for (int n = 0; n < 4; ++n) acc[n] = make_float4(0.f, 0.f, 0.f, 0.f);

    for (int c = 0; c < DIM / WCH; ++c) {
        __syncthreads();   // (c=0: also covers mean_s staging)
        // Stage W chunk transposed: 2048 elements, coalesced global reads
        #pragma unroll
        for (int k = 0; k < (DIM * WCH) / 256; ++k) {
            int idx = t + k * 256;      // 0..2047
            int o   = idx >> 4;         // 0..127
            int il  = idx & 15;         // 0..15
            Ws[il][o] = W[o * DIM + c * WCH + il];
        }
        __syncthreads();

        #pragma unroll
        for (int i = 0; i < WCH; i += 4) {
            float4 m4[4];
            #pragma unroll
            for (int n = 0; n < 4; ++n)
                m4[n] = *reinterpret_cast<const float4*>(&mean_s[ng + n][c * WCH + i]);
            #pragma unroll
            for (int j = 0; j < 4; ++j) {
                float4 w = *reinterpret_cast<const float4*>(&Ws[i + j][og]);
                #pragma unroll
                for (int n = 0; n < 4; ++n) {
                    float m = (j == 0) ? m4[n].x : (j == 1) ? m4[n].y
                            : (j == 2) ? m4[n].z : m4[n].w;
                    acc[n].x += m * w.x;
                    acc[n].y += m * w.y;
                    acc[n].z += m * w.z;
                    acc[n].w += m * w.w;
                }
            }
        }
    }

    float4 bv = *reinterpret_cast<const float4*>(b + og);
    #pragma unroll
    for (int n = 0; n < 4; ++n) {
        int node = base + ng + n;
        float4 xv = *reinterpret_cast<const float4*>(x + (size_t)node * DIM + og);
        float4 o4;
        o4.x = xv.x + bv.x + acc[n].x;
        o4.y = xv.y + bv.y + acc[n].y;
        o4.z = xv.z + bv.z + acc[n].z;
        o4.w = xv.w + bv.w + acc[n].w;
        *reinterpret_cast<float4*>(out + (size_t)node * DIM + og) = o4;
    }
}

extern "C" void kernel_launch(void* const* d_in, const int* in_sizes, int n_in,
                              void* d_out, int out_size, void* d_ws, size_t ws_size,
                              hipStream_t stream) {
    const float* x  = (const float*)d_in[0];
    const int*   ei = (const int*)d_in[1];     // int32 per harness contract
    const float* W  = (const float*)d_in[2];
    const float* b  = (const float*)d_in[3];
    float* out = (float*)d_out;

    unsigned* cnts   = (unsigned*)d_ws;
    unsigned* offs   = cnts + NN;              // NN+1 used (padded to NN+4)
    unsigned* curs   = cnts + 2 * NN + 4;      // NN
    int*      esrc   = (int*)(cnts + 3 * NN + 4);   // NE
    unsigned* blksum = (unsigned*)(esrc + NE);      // 128

    hipMemsetAsync(cnts, 0, (size_t)NN * sizeof(unsigned), stream);

    hist_k  <<<(NE + 255) / 256, 256, 0, stream>>>(ei, cnts);
    scan_a_k<<<NBLK, 256, 0, stream>>>(cnts, blksum);
    scan_c_k<<<NBLK, 256, 0, stream>>>(cnts, blksum, offs, curs);
    bin_k   <<<(NE + 255) / 256, 256, 0, stream>>>(ei, curs, esrc);
    fused_k <<<NN / NPT, 256, 0, stream>>>(x, W, b, offs, esrc, out);
}

// Round 10
// 160.348 us; speedup vs baseline: 3.3089x; 1.0340x over previous
//
#include <hip/hip_runtime.h>

#define NN    100000
#define NE    640000
#define DIM   128
#define NPT   32    // nodes per fused tile
#define PAD   4     // LDS row pad: stride 528 B, 16B-aligned
#define WCH   16    // W chunk width -> Ws 8.4 KB; total LDS 25.3 KB, 6 blk/CU
#define TILE  1024  // scan tile (elements per block)
#define NBLK  98    // ceil(NN / TILE)

// ws layout (4-byte elems), 16B-aligned sections:
//   cnts [0, NN)          offs [NN, 2NN+4)       (NN+1 used)
//   curs [2NN+4, 3NN+4)   esrc [3NN+4, 3NN+4+NE)
//   blksum [+128]         total ~3.77 MB

// ---------------------------------------------------------------------------
// 1) Histogram of targets: 640K int atomics on 100K counters.
// ---------------------------------------------------------------------------
__global__ __launch_bounds__(256) void hist_k(
    const int* __restrict__ ei, unsigned* __restrict__ cnts)
{
    int e = blockIdx.x * 256 + threadIdx.x;
    if (e >= NE) return;
    int t = ei[NE + e];
    if ((unsigned)t >= NN) return;
    atomicAdd(&cnts[t], 1u);
}

// ---------------------------------------------------------------------------
// 2a) Per-block sums of 1024-elem tiles (uint4 loads, shuffle reduce).
// ---------------------------------------------------------------------------
__global__ __launch_bounds__(256) void scan_a_k(
    const unsigned* __restrict__ cnts, unsigned* __restrict__ blksum)
{
    __shared__ unsigned red[4];
    int t    = threadIdx.x;
    int base = blockIdx.x * TILE + t * 4;
    unsigned v = 0;
    if (base + 3 < NN) {
        uint4 u = *reinterpret_cast<const uint4*>(cnts + base);
        v = u.x + u.y + u.z + u.w;
    } else {
        for (int k = 0; k < 4; ++k) if (base + k < NN) v += cnts[base + k];
    }
    #pragma unroll
    for (int off = 32; off; off >>= 1) v += __shfl_down(v, off);
    if ((t & 63) == 0) red[t >> 6] = v;
    __syncthreads();
    if (t == 0) blksum[blockIdx.x] = red[0] + red[1] + red[2] + red[3];
}

// ---------------------------------------------------------------------------
// 2b) Per-block scan (+ inline base from blksum) -> offs, curs.
//     Last block also writes offs[NN].
// ---------------------------------------------------------------------------
__global__ __launch_bounds__(256) void scan_c_k(
    const unsigned* __restrict__ cnts,
    const unsigned* __restrict__ blksum,
    unsigned* __restrict__ offs,
    unsigned* __restrict__ curs)
{
    __shared__ unsigned ps[256];
    __shared__ unsigned lsum[4];
    int t    = threadIdx.x;
    int bid  = blockIdx.x;
    int base = bid * TILE + t * 4;

    unsigned part = 0;
    for (int j = t; j < bid; j += 256) part += blksum[j];
    #pragma unroll
    for (int off = 32; off; off >>= 1) part += __shfl_down(part, off);
    if ((t & 63) == 0) lsum[t >> 6] = part;

    unsigned v0 = 0, v1 = 0, v2 = 0, v3 = 0;
    if (base + 3 < NN) {
        uint4 u = *reinterpret_cast<const uint4*>(cnts + base);
        v0 = u.x; v1 = u.y; v2 = u.z; v3 = u.w;
    } else {
        if (base     < NN) v0 = cnts[base];
        if (base + 1 < NN) v1 = cnts[base + 1];
        if (base + 2 < NN) v2 = cnts[base + 2];
    }
    ps[t] = v0 + v1 + v2 + v3;
    __syncthreads();
    for (int off = 1; off < 256; off <<= 1) {
        unsigned u = (t >= off) ? ps[t - off] : 0u;
        __syncthreads();
        ps[t] += u;
        __syncthreads();
    }
    unsigned blkbase = lsum[0] + lsum[1] + lsum[2] + lsum[3];
    unsigned run = blkbase + ((t == 0) ? 0u : ps[t - 1]);
    unsigned o0 = run, o1 = o0 + v0, o2 = o1 + v1, o3 = o2 + v2;
    if (base + 3 < NN) {
        *reinterpret_cast<uint4*>(offs + base) = make_uint4(o0, o1, o2, o3);
        *reinterpret_cast<uint4*>(curs + base) = make_uint4(o0, o1, o2, o3);
    } else {
        if (base     < NN) { offs[base]     = o0; curs[base]     = o0; }
        if (base + 1 < NN) { offs[base + 1] = o1; curs[base + 1] = o1; }
        if (base + 2 < NN) { offs[base + 2] = o2; curs[base + 2] = o2; }
    }
    if (bid == NBLK - 1 && t == 255) offs[NN] = blkbase + ps[255];
}

// ---------------------------------------------------------------------------
// 3) Bin edges by target: esrc[slot] = src.
// ---------------------------------------------------------------------------
__global__ __launch_bounds__(256) void bin_k(
    const int* __restrict__ ei,
    unsigned* __restrict__ curs,
    int* __restrict__ esrc)
{
    int e = blockIdx.x * 256 + threadIdx.x;
    if (e >= NE) return;
    int s = ei[e];
    int t = ei[NE + e];
    if ((unsigned)s >= NN || (unsigned)t >= NN) return;
    unsigned pos = atomicAdd(&curs[t], 1u);
    esrc[pos] = s;
}

// ---------------------------------------------------------------------------
// 4) Fused mean + linear + residual:
//    out[n] = x[n] + b + (mean over CSR segment of x[src]) @ W^T
//    Mean phase: 8 threads/node, 2-way edge unroll -> 8 outstanding 16B
//    loads/thread (MLP is the lever; occupancy already showed diminishing
//    returns at 54%). LDS: 25.3 KB -> 6 blocks/CU.
// ---------------------------------------------------------------------------
__global__ __launch_bounds__(256) void fused_k(
    const float* __restrict__ x,
    const float* __restrict__ W,        // [o][i] row-major, 128x128
    const float* __restrict__ b,
    const unsigned* __restrict__ offs,
    const int* __restrict__ esrc,
    float* __restrict__ out)
{
    __shared__ float Ws[WCH][DIM + PAD];      // Ws[il][o] = W[o][c*WCH+il]
    __shared__ float mean_s[NPT][DIM + PAD];

    const int t    = threadIdx.x;
    const int base = blockIdx.x * NPT;

    // Compute 32 mean rows: 8 threads/node, 16 floats each, 2-edge unroll.
    {
        int sn   = t >> 3;
        int so   = (t & 7) * 16;
        int node = base + sn;
        unsigned beg = offs[node], end = offs[node + 1];
        float4 a0 = make_float4(0.f, 0.f, 0.f, 0.f), a1 = a0, a2 = a0, a3 = a0;
        float4 c0 = a0, c1 = a0, c2 = a0, c3 = a0;

        unsigned j = beg;
        int s0 = 0, s1 = 0;
        if (j + 1 < end) { s0 = esrc[j]; s1 = esrc[j + 1]; }
        while (j + 1 < end) {
            unsigned jn = j + 2;
            int t0 = 0, t1 = 0;
            if (jn + 1 < end) { t0 = esrc[jn]; t1 = esrc[jn + 1]; }
            const float4* r0 = reinterpret_cast<const float4*>(x + (size_t)s0 * DIM + so);
            const float4* r1 = reinterpret_cast<const float4*>(x + (size_t)s1 * DIM + so);
            float4 g0 = r0[0], g1 = r0[1], g2 = r0[2], g3 = r0[3];
            float4 h0 = r1[0], h1 = r1[1], h2 = r1[2], h3 = r1[3];
            a0.x += g0.x; a0.y += g0.y; a0.z += g0.z; a0.w += g0.w;
            a1.x += g1.x; a1.y += g1.y; a1.z += g1.z; a1.w += g1.w;
            a2.x += g2.x; a2.y += g2.y; a2.z += g2.z; a2.w += g2.w;
            a3.x += g3.x; a3.y += g3.y; a3.z += g3.z; a3.w += g3.w;
            c0.x += h0.x; c0.y += h0.y; c0.z += h0.z; c0.w += h0.w;
            c1.x += h1.x; c1.y += h1.y; c1.z += h1.z; c1.w += h1.w;
            c2.x += h2.x; c2.y += h2.y; c2.z += h2.z; c2.w += h2.w;
            c3.x += h3.x; c3.y += h3.y; c3.z += h3.z; c3.w += h3.w;
            s0 = t0; s1 = t1;
            j = jn;
        }
        if (j < end) {   // odd tail edge
            int s = esrc[j];
            const float4* r0 = reinterpret_cast<const float4*>(x + (size_t)s * DIM + so);
            float4 g0 = r0[0], g1 = r0[1], g2 = r0[2], g3 = r0[3];
            a0.x += g0.x; a0.y += g0.y; a0.z += g0.z; a0.w += g0.w;
            a1.x += g1.x; a1.y += g1.y; a1.z += g1.z; a1.w += g1.w;
            a2.x += g2.x; a2.y += g2.y; a2.z += g2.z; a2.w += g2.w;
            a3.x += g3.x; a3.y += g3.y; a3.z += g3.z; a3.w += g3.w;
        }
        a0.x += c0.x; a0.y += c0.y; a0.z += c0.z; a0.w += c0.w;
        a1.x += c1.x; a1.y += c1.y; a1.z += c1.z; a1.w += c1.w;
        a2.x += c2.x; a2.y += c2.y; a2.z += c2.z; a2.w += c2.w;
        a3.x += c3.x; a3.y += c3.y; a3.z += c3.z; a3.w += c3.w;

        float inv = 1.0f / fmaxf((float)(end - beg), 1.0f);
        a0.x *= inv; a0.y *= inv; a0.z *= inv; a0.w *= inv;
        a1.x *= inv; a1.y *= inv; a1.z *= inv; a1.w *= inv;
        a2.x *= inv; a2.y *= inv; a2.z *= inv; a2.w *= inv;
        a3.x *= inv; a3.y *= inv; a3.z *= inv; a3.w *= inv;
        *reinterpret_cast<float4*>(&mean_s[sn][so +  0]) = a0;
        *reinterpret_cast<float4*>(&mean_s[sn][so +  4]) = a1;
        *reinterpret_cast<float4*>(&mean_s[sn][so +  8]) = a2;
        *reinterpret_cast<float4*>(&mean_s[sn][so + 12]) = a3;
    }

    const int og = (t & 31) * 4;    // 4 consecutive outputs per thread
    const int ng = (t >> 5) * 4;    // 4 consecutive nodes per thread

    float4 acc[4];
    #pragma unroll
    for (int n = 0; n < 4; ++n) acc[n] = make_float4(0.f, 0.f, 0.f, 0.f);

    for (int c = 0; c < DIM / WCH; ++c) {
        __syncthreads();   // (c=0: also covers mean_s staging)
        #pragma unroll
        for (int k = 0; k < (DIM * WCH) / 256; ++k) {
            int idx = t + k * 256;      // 0..2047
            int o   = idx >> 4;         // 0..127
            int il  = idx & 15;         // 0..15
            Ws[il][o] = W[o * DIM + c * WCH + il];
        }
        __syncthreads();

        #pragma unroll
        for (int i = 0; i < WCH; i += 4) {
            float4 m4[4];
            #pragma unroll
            for (int n = 0; n < 4; ++n)
                m4[n] = *reinterpret_cast<const float4*>(&mean_s[ng + n][c * WCH + i]);
            #pragma unroll
            for (int j = 0; j < 4; ++j) {
                float4 w = *reinterpret_cast<const float4*>(&Ws[i + j][og]);
                #pragma unroll
                for (int n = 0; n < 4; ++n) {
                    float m = (j == 0) ? m4[n].x : (j == 1) ? m4[n].y
                            : (j == 2) ? m4[n].z : m4[n].w;
                    acc[n].x += m * w.x;
                    acc[n].y += m * w.y;
                    acc[n].z += m * w.z;
                    acc[n].w += m * w.w;
                }
            }
        }
    }

    float4 bv = *reinterpret_cast<const float4*>(b + og);
    #pragma unroll
    for (int n = 0; n < 4; ++n) {
        int node = base + ng + n;
        float4 xv = *reinterpret_cast<const float4*>(x + (size_t)node * DIM + og);
        float4 o4;
        o4.x = xv.x + bv.x + acc[n].x;
        o4.y = xv.y + bv.y + acc[n].y;
        o4.z = xv.z + bv.z + acc[n].z;
        o4.w = xv.w + bv.w + acc[n].w;
        *reinterpret_cast<float4*>(out + (size_t)node * DIM + og) = o4;
    }
}

extern "C" void kernel_launch(void* const* d_in, const int* in_sizes, int n_in,
                              void* d_out, int out_size, void* d_ws, size_t ws_size,
                              hipStream_t stream) {
    const float* x  = (const float*)d_in[0];
    const int*   ei = (const int*)d_in[1];     // int32 per harness contract
    const float* W  = (const float*)d_in[2];
    const float* b  = (const float*)d_in[3];
    float* out = (float*)d_out;

    unsigned* cnts   = (unsigned*)d_ws;
    unsigned* offs   = cnts + NN;              // NN+1 used (padded to NN+4)
    unsigned* curs   = cnts + 2 * NN + 4;      // NN
    int*      esrc   = (int*)(cnts + 3 * NN + 4);   // NE
    unsigned* blksum = (unsigned*)(esrc + NE);      // 128

    hipMemsetAsync(cnts, 0, (size_t)NN * sizeof(unsigned), stream);

    hist_k  <<<(NE + 255) / 256, 256, 0, stream>>>(ei, cnts);
    scan_a_k<<<NBLK, 256, 0, stream>>>(cnts, blksum);
    scan_c_k<<<NBLK, 256, 0, stream>>>(cnts, blksum, offs, curs);
    bin_k   <<<(NE + 255) / 256, 256, 0, stream>>>(ei, curs, esrc);
    fused_k <<<NN / NPT, 256, 0, stream>>>(x, W, b, offs, esrc, out);
}